// Round 2
// baseline (3488.779 us; speedup 1.0000x reference)
//
#include <hip/hip_runtime.h>
#include <hip/hip_bf16.h>

__device__ __forceinline__ float waveReduceSum(float v) {
#pragma unroll
    for (int off = 32; off > 0; off >>= 1) v += __shfl_down(v, off, 64);
    return __shfl(v, 0, 64);
}

// ---------------------------------------------------------------------------
// Stage dims
// ---------------------------------------------------------------------------
#define NB   64
#define T1   3136   // 56*56
#define T2   784    // 28*28
#define T3   196    // 14*14
#define EMB  64
#define MRF  32
#define D1   147
#define D2   576

// ---------------------------------------------------------------------------
// front1: unfold(7,4,2) from x + LN + kqv + prm_exp. One 64-thread wave/token.
// ---------------------------------------------------------------------------
__global__ __launch_bounds__(64) void front1(
    const float* __restrict__ x,
    const float* __restrict__ kqv_w,  // (147,192)
    const float* __restrict__ kqv_b,  // (192)
    const float* __restrict__ ln_g, const float* __restrict__ ln_b,  // (147)
    const float* __restrict__ rf,     // (32,64)
    float* __restrict__ kp, float* __restrict__ qp,  // (B,T1,32)
    float* __restrict__ v_out)                       // (B,T1,64)
{
    const int tok = blockIdx.x;
    const int b = tok / T1, t = tok % T1;
    const int py = t / 56, px = t % 56;
    const int tid = threadIdx.x;

    __shared__ float f[D1];
    __shared__ float kq[128];

    for (int d = tid; d < D1; d += 64) {
        int c = d / 49, r = d % 49, ki = r / 7, kj = r % 7;
        int iy = py * 4 - 2 + ki, ix = px * 4 - 2 + kj;
        float val = 0.f;
        if (iy >= 0 && iy < 224 && ix >= 0 && ix < 224)
            val = x[((b * 3 + c) * 224 + iy) * 224 + ix];
        f[d] = val;
    }
    __syncthreads();

    float s = 0.f, s2 = 0.f;
    for (int d = tid; d < D1; d += 64) { float u = f[d]; s += u; s2 += u * u; }
    s = waveReduceSum(s);
    s2 = waveReduceSum(s2);
    const float mu = s * (1.f / D1);
    const float var = s2 * (1.f / D1) - mu * mu;
    const float rstd = rsqrtf(var + 1e-5f);
    for (int d = tid; d < D1; d += 64)
        f[d] = (f[d] - mu) * rstd * ln_g[d] + ln_b[d];
    __syncthreads();

    const int e = tid;
    float k = kqv_b[e], q = kqv_b[64 + e], vv = kqv_b[128 + e];
    for (int d = 0; d < D1; ++d) {
        const float xv = f[d];
        const float* wrow = kqv_w + d * 192;
        k  += xv * wrow[e];
        q  += xv * wrow[64 + e];
        vv += xv * wrow[128 + e];
    }
    const int base = b * T1 + t;
    v_out[base * 64 + e] = vv;
    kq[e] = k; kq[64 + e] = q;
    const float xdk = 0.5f * waveReduceSum(k * k);
    const float xdq = 0.5f * waveReduceSum(q * q);
    __syncthreads();

    const int half = tid >> 5, mm = tid & 31;
    const float* vec = &kq[half * 64];
    const float xd = half ? xdq : xdk;
    float acc = 0.f;
#pragma unroll
    for (int d = 0; d < 64; ++d) acc += rf[mm * 64 + d] * vec[d];
    const float p = expf(acc - xd) * 0.1767766952966369f;  // 1/sqrt(32)
    (half ? qp : kp)[base * 32 + mm] = p;
}

// ---------------------------------------------------------------------------
// front2: unfold(3,2,1) from out1 (B,T1,64 == B,64,56,56 chan-last) + LN + kqv
// + prm_exp. One wave per token (T2 tokens).
// ---------------------------------------------------------------------------
__global__ __launch_bounds__(64) void front2(
    const float* __restrict__ src,   // out1 (B,3136,64)
    const float* __restrict__ kqv_w,  // (576,192)
    const float* __restrict__ kqv_b,
    const float* __restrict__ ln_g, const float* __restrict__ ln_b,  // (576)
    const float* __restrict__ rf,
    float* __restrict__ kp, float* __restrict__ qp,  // (B,T2,32)
    float* __restrict__ v_out)                       // (B,T2,64)
{
    const int tok = blockIdx.x;
    const int b = tok / T2, t = tok % T2;
    const int py = t / 28, px = t % 28;
    const int tid = threadIdx.x;

    __shared__ float f[D2];
    __shared__ float kq[128];

    for (int d = tid; d < D2; d += 64) {
        int c = d / 9, r = d % 9, ki = r / 3, kj = r % 3;
        int iy = py * 2 - 1 + ki, ix = px * 2 - 1 + kj;
        float val = 0.f;
        if (iy >= 0 && iy < 56 && ix >= 0 && ix < 56)
            val = src[(b * T1 + iy * 56 + ix) * 64 + c];
        f[d] = val;
    }
    __syncthreads();

    float s = 0.f, s2 = 0.f;
    for (int d = tid; d < D2; d += 64) { float u = f[d]; s += u; s2 += u * u; }
    s = waveReduceSum(s);
    s2 = waveReduceSum(s2);
    const float mu = s * (1.f / D2);
    const float var = s2 * (1.f / D2) - mu * mu;
    const float rstd = rsqrtf(var + 1e-5f);
    for (int d = tid; d < D2; d += 64)
        f[d] = (f[d] - mu) * rstd * ln_g[d] + ln_b[d];
    __syncthreads();

    const int e = tid;
    float k = kqv_b[e], q = kqv_b[64 + e], vv = kqv_b[128 + e];
    for (int d = 0; d < D2; ++d) {
        const float xv = f[d];
        const float* wrow = kqv_w + d * 192;
        k  += xv * wrow[e];
        q  += xv * wrow[64 + e];
        vv += xv * wrow[128 + e];
    }
    const int base = b * T2 + t;
    v_out[base * 64 + e] = vv;
    kq[e] = k; kq[64 + e] = q;
    const float xdk = 0.5f * waveReduceSum(k * k);
    const float xdq = 0.5f * waveReduceSum(q * q);
    __syncthreads();

    const int half = tid >> 5, mm = tid & 31;
    const float* vec = &kq[half * 64];
    const float xd = half ? xdq : xdk;
    float acc = 0.f;
#pragma unroll
    for (int d = 0; d < 64; ++d) acc += rf[mm * 64 + d] * vec[d];
    const float p = expf(acc - xd) * 0.1767766952966369f;
    (half ? qp : kp)[base * 32 + mm] = p;
}

// ---------------------------------------------------------------------------
// reduce_kv: ksum[b,m] = sum_t kp[b,t,m];  kptv[b,n,m] = sum_t v[b,t,n]*kp[b,t,m]
// one block per batch.
// ---------------------------------------------------------------------------
template <int T>
__global__ __launch_bounds__(256) void reduce_kv(
    const float* __restrict__ kp, const float* __restrict__ v,
    float* __restrict__ ksum,   // (B,32)
    float* __restrict__ kptv)   // (B,64,32)
{
    const int b = blockIdx.x;
    const int tid = threadIdx.x;
    __shared__ float kp_s[8][32];
    __shared__ float v_s[8][64];
    float acc[8] = {0.f, 0.f, 0.f, 0.f, 0.f, 0.f, 0.f, 0.f};
    float ks = 0.f;
    const int n = tid >> 2;
    const int mb = (tid & 3) * 8;
    const float* kpb = kp + (size_t)b * T * 32;
    const float* vb  = v  + (size_t)b * T * 64;

    for (int t0 = 0; t0 < T; t0 += 8) {
        kp_s[tid >> 5][tid & 31] = kpb[(t0 + (tid >> 5)) * 32 + (tid & 31)];
        {
            const int i0 = tid * 2, i1 = tid * 2 + 1;
            v_s[i0 >> 6][i0 & 63] = vb[(t0 + (i0 >> 6)) * 64 + (i0 & 63)];
            v_s[i1 >> 6][i1 & 63] = vb[(t0 + (i1 >> 6)) * 64 + (i1 & 63)];
        }
        __syncthreads();
#pragma unroll
        for (int tt = 0; tt < 8; ++tt) {
            const float vv = v_s[tt][n];
#pragma unroll
            for (int i = 0; i < 8; ++i) acc[i] += vv * kp_s[tt][mb + i];
        }
        if (tid < 32) {
#pragma unroll
            for (int tt = 0; tt < 8; ++tt) ks += kp_s[tt][tid];
        }
        __syncthreads();
    }
#pragma unroll
    for (int i = 0; i < 8; ++i) kptv[(b * 64 + n) * 32 + mb + i] = acc[i];
    if (tid < 32) ksum[b * 32 + tid] = ks;
}

// ---------------------------------------------------------------------------
// epilogue: y_attn = (qp @ kptv^T)/(D+eps); y = v + proj(y_attn)+pb;
// out = y + m2(gelu(m1(LN(y))+b1))+b2.  One wave per token.
// ---------------------------------------------------------------------------
template <int T>
__global__ __launch_bounds__(64) void epilogue(
    const float* __restrict__ qp, const float* __restrict__ v,
    const float* __restrict__ ksum, const float* __restrict__ kptv,
    const float* __restrict__ proj_w, const float* __restrict__ proj_b,
    const float* __restrict__ ln2_g, const float* __restrict__ ln2_b,
    const float* __restrict__ m1_w, const float* __restrict__ m1_b,
    const float* __restrict__ m2_w, const float* __restrict__ m2_b,
    float* __restrict__ out)   // (B,T,64)
{
    const int tok = blockIdx.x;
    const int b = tok / T, t = tok % T;
    const int e = threadIdx.x;
    const int base = b * T + t;

    __shared__ float qp_s[32];
    __shared__ float sh[64];

    if (e < 32) qp_s[e] = qp[base * 32 + e];
    __syncthreads();

    const float* ks = ksum + b * 32;
    float D = 1e-8f;
#pragma unroll
    for (int m = 0; m < 32; ++m) D += qp_s[m] * ks[m];

    const float* kv = kptv + (b * 64 + e) * 32;
    float ya = 0.f;
#pragma unroll
    for (int m = 0; m < 32; ++m) ya += qp_s[m] * kv[m];
    ya /= D;
    sh[e] = ya;
    __syncthreads();

    float a = proj_b[e];
    for (int j = 0; j < 64; ++j) a += sh[j] * proj_w[j * 64 + e];
    const float y = v[base * 64 + e] + a;
    __syncthreads();

    // LN over 64
    const float s  = waveReduceSum(y);
    const float s2 = waveReduceSum(y * y);
    const float mu = s * (1.f / 64.f);
    const float var = s2 * (1.f / 64.f) - mu * mu;
    const float z = (y - mu) * rsqrtf(var + 1e-5f) * ln2_g[e] + ln2_b[e];
    sh[e] = z;
    __syncthreads();

    float a1 = m1_b[e];
    for (int j = 0; j < 64; ++j) a1 += sh[j] * m1_w[j * 64 + e];
    a1 = 0.5f * a1 * (1.f + erff(a1 * 0.7071067811865476f));
    __syncthreads();
    sh[e] = a1;
    __syncthreads();

    float a2 = m2_b[e];
    for (int j = 0; j < 64; ++j) a2 += sh[j] * m2_w[j * 64 + e];
    out[base * 64 + e] = y + a2;
}

// ---------------------------------------------------------------------------
// final: unfold(3,2,1) from out2 (B,T2,64 == B,64,28,28 chan-last), then
// (576)->(768) dense, f32 out. One 256-thread block per token.
// ---------------------------------------------------------------------------
__global__ __launch_bounds__(256) void final_proj(
    const float* __restrict__ out2,  // (B,784,64)
    const float* __restrict__ w,     // (576,768)
    const float* __restrict__ bias,  // (768)
    float* __restrict__ out)         // (B,196,768)
{
    const int tok = blockIdx.x;
    const int b = tok / T3, t = tok % T3;
    const int py = t / 14, px = t % 14;
    const int tid = threadIdx.x;

    __shared__ float f[D2];
    for (int d = tid; d < D2; d += 256) {
        int c = d / 9, r = d % 9, ki = r / 3, kj = r % 3;
        int iy = py * 2 - 1 + ki, ix = px * 2 - 1 + kj;
        float val = 0.f;
        if (iy >= 0 && iy < 28 && ix >= 0 && ix < 28)
            val = out2[(b * T2 + iy * 28 + ix) * 64 + c];
        f[d] = val;
    }
    __syncthreads();

    for (int o = tid; o < 768; o += 256) {
        float a = bias[o];
        for (int d = 0; d < D2; ++d) a += f[d] * w[d * 768 + o];
        out[(b * T3 + t) * 768 + o] = a;
    }
}

// ---------------------------------------------------------------------------
extern "C" void kernel_launch(void* const* d_in, const int* in_sizes, int n_in,
                              void* d_out, int out_size, void* d_ws, size_t ws_size,
                              hipStream_t stream) {
    const float* x         = (const float*)d_in[0];
    const float* p1_kqv_w  = (const float*)d_in[1];
    const float* p1_kqv_b  = (const float*)d_in[2];
    const float* p1_proj_w = (const float*)d_in[3];
    const float* p1_proj_b = (const float*)d_in[4];
    const float* p1_ln1_g  = (const float*)d_in[5];
    const float* p1_ln1_b  = (const float*)d_in[6];
    const float* p1_ln2_g  = (const float*)d_in[7];
    const float* p1_ln2_b  = (const float*)d_in[8];
    const float* p1_m1_w   = (const float*)d_in[9];
    const float* p1_m1_b   = (const float*)d_in[10];
    const float* p1_m2_w   = (const float*)d_in[11];
    const float* p1_m2_b   = (const float*)d_in[12];
    const float* p1_rf     = (const float*)d_in[13];
    const float* p2_kqv_w  = (const float*)d_in[14];
    const float* p2_kqv_b  = (const float*)d_in[15];
    const float* p2_proj_w = (const float*)d_in[16];
    const float* p2_proj_b = (const float*)d_in[17];
    const float* p2_ln1_g  = (const float*)d_in[18];
    const float* p2_ln1_b  = (const float*)d_in[19];
    const float* p2_ln2_g  = (const float*)d_in[20];
    const float* p2_ln2_b  = (const float*)d_in[21];
    const float* p2_m1_w   = (const float*)d_in[22];
    const float* p2_m1_b   = (const float*)d_in[23];
    const float* p2_m2_w   = (const float*)d_in[24];
    const float* p2_m2_b   = (const float*)d_in[25];
    const float* p2_rf     = (const float*)d_in[26];
    const float* proj_w    = (const float*)d_in[27];
    const float* proj_b    = (const float*)d_in[28];

    float* ws = (float*)d_ws;
    size_t off = 0;
    // Stage-1 buffers
    float* kp1   = ws + off; off += (size_t)NB * T1 * 32;   // dead after reduce_kv1
    float* qp1   = ws + off; off += (size_t)NB * T1 * 32;   // dead after epilogue1
    float* v1    = ws + off; off += (size_t)NB * T1 * 64;   // dead after epilogue1
    float* o1    = ws + off; off += (size_t)NB * T1 * 64;   // dead after front2
    float* ksum1 = ws + off; off += (size_t)NB * 32;
    float* kptv1 = ws + off; off += (size_t)NB * 64 * 32;
    // Stage-2 buffers alias the dead stage-1 region (kp1..v1 = 25.7M floats,
    // stage-2 needs only 9.7M).
    size_t off2 = 0;
    float* kp2   = kp1 + off2; off2 += (size_t)NB * T2 * 32;
    float* qp2   = kp1 + off2; off2 += (size_t)NB * T2 * 32;
    float* v2    = kp1 + off2; off2 += (size_t)NB * T2 * 64;
    float* o2    = kp1 + off2; off2 += (size_t)NB * T2 * 64;
    float* ksum2 = kp1 + off2; off2 += (size_t)NB * 32;
    float* kptv2 = kp1 + off2; off2 += (size_t)NB * 64 * 32;

    front1<<<NB * T1, 64, 0, stream>>>(x, p1_kqv_w, p1_kqv_b, p1_ln1_g, p1_ln1_b,
                                       p1_rf, kp1, qp1, v1);
    reduce_kv<T1><<<NB, 256, 0, stream>>>(kp1, v1, ksum1, kptv1);
    epilogue<T1><<<NB * T1, 64, 0, stream>>>(qp1, v1, ksum1, kptv1,
                                             p1_proj_w, p1_proj_b, p1_ln2_g, p1_ln2_b,
                                             p1_m1_w, p1_m1_b, p1_m2_w, p1_m2_b, o1);
    front2<<<NB * T2, 64, 0, stream>>>(o1, p2_kqv_w, p2_kqv_b, p2_ln1_g, p2_ln1_b,
                                       p2_rf, kp2, qp2, v2);
    reduce_kv<T2><<<NB, 256, 0, stream>>>(kp2, v2, ksum2, kptv2);
    epilogue<T2><<<NB * T2, 64, 0, stream>>>(qp2, v2, ksum2, kptv2,
                                             p2_proj_w, p2_proj_b, p2_ln2_g, p2_ln2_b,
                                             p2_m1_w, p2_m1_b, p2_m2_w, p2_m2_b, o2);
    final_proj<<<NB * T3, 256, 0, stream>>>(o2, proj_w, proj_b, (float*)d_out);
}

// Round 3
// 1501.245 us; speedup vs baseline: 2.3239x; 2.3239x over previous
//
#include <hip/hip_runtime.h>
#include <hip/hip_bf16.h>

#define NB 64
#define T1 3136
#define T2 784
#define T3 196
#define D1 147
#define D2 576

__device__ __forceinline__ float waveReduceSum(float v) {
#pragma unroll
    for (int off = 32; off > 0; off >>= 1) v += __shfl_down(v, off, 64);
    return __shfl(v, 0, 64);
}

// ---------------------------------------------------------------------------
// front1: 32 tokens/block, 192 threads. unfold(7,4,2) + LN + kqv + prm_exp.
// Thread owns output column e (0..191); weights loaded once per block-tile.
// ---------------------------------------------------------------------------
__global__ __launch_bounds__(192) void front1(
    const float* __restrict__ x,
    const float* __restrict__ kqv_w,   // (147,192)
    const float* __restrict__ kqv_b,   // (192)
    const float* __restrict__ ln_g, const float* __restrict__ ln_b,  // (147)
    const float* __restrict__ rf,      // (32,64)
    float* __restrict__ kp, float* __restrict__ qp,   // (B*T1,32)
    float* __restrict__ v_out)                        // (B*T1,64)
{
    const int tok0 = blockIdx.x * 32;
    const int b = tok0 / T1;
    const int tbase = tok0 % T1;   // T1 % 32 == 0, no straddle
    const int tid = threadIdx.x;

    __shared__ __align__(16) float ft[D1 * 36];      // [d][m], pad 36
    __shared__ float g_s[D1], b_s[D1];
    __shared__ __align__(16) float rf_s[32 * 68];    // [mrf][e], pad 68
    __shared__ __align__(16) float kq_s[2 * 32 * 68];// [half][m][e], pad 68
    __shared__ float ps_sum[192], ps_sq[192];
    __shared__ float mu_s[32], rs_s[32];
    __shared__ float xd_s[2 * 32];

    for (int i = tid; i < D1; i += 192) { g_s[i] = ln_g[i]; b_s[i] = ln_b[i]; }
    for (int i = tid; i < 2048; i += 192) rf_s[(i >> 6) * 68 + (i & 63)] = rf[i];

    // unfold gather -> ft[d*36+m] (consecutive lanes -> consecutive m: LDS
    // writes conflict-free)
    for (int idx = tid; idx < D1 * 32; idx += 192) {
        const int m = idx & 31, d = idx >> 5;
        const int t = tbase + m;
        const int py = t / 56, px = t % 56;
        const int c = d / 49, r = d % 49, ki = r / 7, kj = r % 7;
        const int iy = py * 4 - 2 + ki, ix = px * 4 - 2 + kj;
        float val = 0.f;
        if (iy >= 0 && iy < 224 && ix >= 0 && ix < 224)
            val = x[((b * 3 + c) * 224 + iy) * 224 + ix];
        ft[d * 36 + m] = val;
    }
    __syncthreads();

    // LN: 6 partial pieces per token
    { const int m = tid & 31, j = tid >> 5;
      float s = 0.f, s2 = 0.f;
      for (int d = j; d < D1; d += 6) { const float u = ft[d*36+m]; s += u; s2 += u*u; }
      ps_sum[tid] = s; ps_sq[tid] = s2; }
    __syncthreads();
    if (tid < 32) {
        float s = 0.f, s2 = 0.f;
        for (int j = 0; j < 6; ++j) { s += ps_sum[j*32+tid]; s2 += ps_sq[j*32+tid]; }
        const float mu = s * (1.f / D1);
        const float var = s2 * (1.f / D1) - mu * mu;
        mu_s[tid] = mu; rs_s[tid] = rsqrtf(var + 1e-5f);
    }
    __syncthreads();
    for (int idx = tid; idx < D1 * 32; idx += 192) {
        const int m = idx & 31, d = idx >> 5;
        ft[d*36+m] = (ft[d*36+m] - mu_s[m]) * rs_s[m] * g_s[d] + b_s[d];
    }
    __syncthreads();

    // matvec: acc[m] for 32 tokens, weight column e loaded once per d
    const int e = tid;
    float acc[32];
    { const float bias = kqv_b[e];
#pragma unroll
      for (int m = 0; m < 32; ++m) acc[m] = bias; }
    for (int d = 0; d < D1; ++d) {
        const float w = kqv_w[d * 192 + e];
        const float4* f4 = (const float4*)&ft[d * 36];
#pragma unroll
        for (int g = 0; g < 8; ++g) {
            const float4 f = f4[g];
            acc[4*g+0] += f.x * w; acc[4*g+1] += f.y * w;
            acc[4*g+2] += f.z * w; acc[4*g+3] += f.w * w;
        }
    }
    const int wave = tid >> 6, lane = tid & 63;
    if (wave == 2) {
#pragma unroll
        for (int m = 0; m < 32; ++m)
            v_out[(size_t)(tok0 + m) * 64 + lane] = acc[m];
    } else {
#pragma unroll
        for (int m = 0; m < 32; ++m) kq_s[(wave * 32 + m) * 68 + lane] = acc[m];
#pragma unroll
        for (int m = 0; m < 32; ++m) {
            const float s = waveReduceSum(acc[m] * acc[m]);
            if (lane == 0) xd_s[wave * 32 + m] = 0.5f * s;
        }
    }
    __syncthreads();

    // prm_exp: 2048 (half,m,mrf) slots over 192 threads
    for (int slot = tid; slot < 2048; slot += 192) {
        const int half = slot >> 10, rem = slot & 1023;
        const int m = rem >> 5, mrf = rem & 31;
        const float4* r4 = (const float4*)&rf_s[mrf * 68];
        const float4* k4 = (const float4*)&kq_s[(half * 32 + m) * 68];
        float a = 0.f;
#pragma unroll
        for (int g = 0; g < 16; ++g) {
            const float4 rv = r4[g], kv = k4[g];
            a += rv.x*kv.x + rv.y*kv.y + rv.z*kv.z + rv.w*kv.w;
        }
        const float p = expf(a - xd_s[half * 32 + m]) * 0.1767766952966369f;
        (half ? qp : kp)[(size_t)(tok0 + m) * 32 + mrf] = p;
    }
}

// ---------------------------------------------------------------------------
// front2: 16 tokens/block, 192 threads. unfold(3,2,1) from o1 + LN + kqv +
// prm_exp. Same structure, D=576.
// ---------------------------------------------------------------------------
__global__ __launch_bounds__(192) void front2(
    const float* __restrict__ src,     // o1 (B*T1,64) == (B,64,56,56) ch-last
    const float* __restrict__ kqv_w,   // (576,192)
    const float* __restrict__ kqv_b,
    const float* __restrict__ ln_g, const float* __restrict__ ln_b,  // (576)
    const float* __restrict__ rf,
    float* __restrict__ kp, float* __restrict__ qp,   // (B*T2,32)
    float* __restrict__ v_out)                        // (B*T2,64)
{
    const int tok0 = blockIdx.x * 16;
    const int b = tok0 / T2;
    const int tbase = tok0 % T2;   // T2 % 16 == 0
    const int tid = threadIdx.x;

    __shared__ __align__(16) float ft[D2 * 20];      // [d][m], pad 20
    __shared__ float g_s[D2], b_s[D2];
    __shared__ __align__(16) float rf_s[32 * 68];
    __shared__ __align__(16) float kq_s[2 * 16 * 68];
    __shared__ float ps_sum[192], ps_sq[192];
    __shared__ float mu_s[16], rs_s[16];
    __shared__ float xd_s[2 * 16];

    for (int i = tid; i < D2; i += 192) { g_s[i] = ln_g[i]; b_s[i] = ln_b[i]; }
    for (int i = tid; i < 2048; i += 192) rf_s[(i >> 6) * 68 + (i & 63)] = rf[i];

    // gather: lanes own channel c (coalesced src reads, 256B per instr)
    { const int c = tid & 63, grp = tid >> 6;   // grp 0..2
      for (int u = grp; u < 16 * 9; u += 3) {
          const int m = u / 9, r = u % 9;
          const int t = tbase + m;
          const int py = t / 28, px = t % 28;
          const int ki = r / 3, kj = r % 3;
          const int iy = py * 2 - 1 + ki, ix = px * 2 - 1 + kj;
          float val = 0.f;
          if (iy >= 0 && iy < 56 && ix >= 0 && ix < 56)
              val = src[(size_t)(b * T1 + iy * 56 + ix) * 64 + c];
          ft[(c * 9 + r) * 20 + m] = val;
      }
    }
    __syncthreads();

    { const int m = tid & 15, j = tid >> 4;   // j 0..11
      float s = 0.f, s2 = 0.f;
      for (int d = j; d < D2; d += 12) { const float u = ft[d*20+m]; s += u; s2 += u*u; }
      ps_sum[tid] = s; ps_sq[tid] = s2; }
    __syncthreads();
    if (tid < 16) {
        float s = 0.f, s2 = 0.f;
        for (int j = 0; j < 12; ++j) { s += ps_sum[j*16+tid]; s2 += ps_sq[j*16+tid]; }
        const float mu = s * (1.f / D2);
        const float var = s2 * (1.f / D2) - mu * mu;
        mu_s[tid] = mu; rs_s[tid] = rsqrtf(var + 1e-5f);
    }
    __syncthreads();
    for (int idx = tid; idx < D2 * 16; idx += 192) {
        const int m = idx & 15, d = idx >> 4;
        ft[d*20+m] = (ft[d*20+m] - mu_s[m]) * rs_s[m] * g_s[d] + b_s[d];
    }
    __syncthreads();

    const int e = tid;
    float acc[16];
    { const float bias = kqv_b[e];
#pragma unroll
      for (int m = 0; m < 16; ++m) acc[m] = bias; }
    for (int d = 0; d < D2; ++d) {
        const float w = kqv_w[d * 192 + e];
        const float4* f4 = (const float4*)&ft[d * 20];
#pragma unroll
        for (int g = 0; g < 4; ++g) {
            const float4 f = f4[g];
            acc[4*g+0] += f.x * w; acc[4*g+1] += f.y * w;
            acc[4*g+2] += f.z * w; acc[4*g+3] += f.w * w;
        }
    }
    const int wave = tid >> 6, lane = tid & 63;
    if (wave == 2) {
#pragma unroll
        for (int m = 0; m < 16; ++m)
            v_out[(size_t)(tok0 + m) * 64 + lane] = acc[m];
    } else {
#pragma unroll
        for (int m = 0; m < 16; ++m) kq_s[(wave * 16 + m) * 68 + lane] = acc[m];
#pragma unroll
        for (int m = 0; m < 16; ++m) {
            const float s = waveReduceSum(acc[m] * acc[m]);
            if (lane == 0) xd_s[wave * 16 + m] = 0.5f * s;
        }
    }
    __syncthreads();

    for (int slot = tid; slot < 1024; slot += 192) {
        const int half = slot >> 9, rem = slot & 511;
        const int m = rem >> 5, mrf = rem & 31;
        const float4* r4 = (const float4*)&rf_s[mrf * 68];
        const float4* k4 = (const float4*)&kq_s[(half * 16 + m) * 68];
        float a = 0.f;
#pragma unroll
        for (int g = 0; g < 16; ++g) {
            const float4 rv = r4[g], kv = k4[g];
            a += rv.x*kv.x + rv.y*kv.y + rv.z*kv.z + rv.w*kv.w;
        }
        const float p = expf(a - xd_s[half * 16 + m]) * 0.1767766952966369f;
        (half ? qp : kp)[(size_t)(tok0 + m) * 32 + mrf] = p;
    }
}

// ---------------------------------------------------------------------------
// reduce_kv, split S-ways over T with atomics (ksum/kptv pre-zeroed)
// ---------------------------------------------------------------------------
template <int T, int S>
__global__ __launch_bounds__(256) void reduce_kv(
    const float* __restrict__ kp, const float* __restrict__ v,
    float* __restrict__ ksum,   // (B,32)
    float* __restrict__ kptv)   // (B,64,32)
{
    const int b = blockIdx.x / S, s = blockIdx.x % S;
    const int chunk = T / S;    // multiple of 8 by construction
    const int tid = threadIdx.x;
    __shared__ float kp_s[8][32];
    __shared__ float v_s[8][64];
    float acc[8] = {0.f, 0.f, 0.f, 0.f, 0.f, 0.f, 0.f, 0.f};
    float ks = 0.f;
    const int n = tid >> 2;
    const int mb = (tid & 3) * 8;
    const float* kpb = kp + (size_t)b * T * 32;
    const float* vb  = v  + (size_t)b * T * 64;

    for (int t0 = s * chunk; t0 < (s + 1) * chunk; t0 += 8) {
        kp_s[tid >> 5][tid & 31] = kpb[(t0 + (tid >> 5)) * 32 + (tid & 31)];
        {
            const int i0 = tid * 2, i1 = tid * 2 + 1;
            v_s[i0 >> 6][i0 & 63] = vb[(t0 + (i0 >> 6)) * 64 + (i0 & 63)];
            v_s[i1 >> 6][i1 & 63] = vb[(t0 + (i1 >> 6)) * 64 + (i1 & 63)];
        }
        __syncthreads();
#pragma unroll
        for (int tt = 0; tt < 8; ++tt) {
            const float vv = v_s[tt][n];
#pragma unroll
            for (int i = 0; i < 8; ++i) acc[i] += vv * kp_s[tt][mb + i];
        }
        if (tid < 32) {
#pragma unroll
            for (int tt = 0; tt < 8; ++tt) ks += kp_s[tt][tid];
        }
        __syncthreads();
    }
#pragma unroll
    for (int i = 0; i < 8; ++i) atomicAdd(&kptv[(b * 64 + n) * 32 + mb + i], acc[i]);
    if (tid < 32) atomicAdd(&ksum[b * 32 + tid], ks);
}

// ---------------------------------------------------------------------------
// epilogue: 16 tokens/wave-block. attention readout + proj + LN + MLP.
// ---------------------------------------------------------------------------
template <int T>
__global__ __launch_bounds__(64) void epilogue(
    const float* __restrict__ qp, const float* __restrict__ v,
    const float* __restrict__ ksum, const float* __restrict__ kptv,
    const float* __restrict__ proj_w, const float* __restrict__ proj_b,
    const float* __restrict__ ln2_g, const float* __restrict__ ln2_b,
    const float* __restrict__ m1_w, const float* __restrict__ m1_b,
    const float* __restrict__ m2_w, const float* __restrict__ m2_b,
    float* __restrict__ out)   // (B*T,64)
{
    const int tok0 = blockIdx.x * 16;
    const int b = tok0 / T;    // T % 16 == 0
    const int e = threadIdx.x;

    __shared__ __align__(16) float qp_s[16 * 36];   // [m][mrf] pad 36
    __shared__ __align__(16) float buf[64 * 20];    // [j][m]  pad 20
    __shared__ float ks_s[32];
    __shared__ float D_s[16];

    for (int idx = e; idx < 512; idx += 64)
        qp_s[(idx >> 5) * 36 + (idx & 31)] = qp[(size_t)tok0 * 32 + idx];
    if (e < 32) ks_s[e] = ksum[b * 32 + e];
    __syncthreads();
    if (e < 16) {
        float D = 1e-8f;
        for (int r = 0; r < 32; ++r) D += qp_s[e * 36 + r] * ks_s[r];
        D_s[e] = D;
    }
    float4 kv4[8];
#pragma unroll
    for (int g = 0; g < 8; ++g)
        kv4[g] = *(const float4*)&kptv[(size_t)(b * 64 + e) * 32 + 4 * g];
    __syncthreads();

    float ya[16];
#pragma unroll
    for (int m = 0; m < 16; ++m) {
        const float4* q4 = (const float4*)&qp_s[m * 36];
        float a = 0.f;
#pragma unroll
        for (int g = 0; g < 8; ++g) {
            const float4 qv = q4[g];
            a += qv.x*kv4[g].x + qv.y*kv4[g].y + qv.z*kv4[g].z + qv.w*kv4[g].w;
        }
        ya[m] = a / D_s[m];
    }
#pragma unroll
    for (int g = 0; g < 4; ++g)
        *(float4*)&buf[e * 20 + 4*g] = make_float4(ya[4*g], ya[4*g+1], ya[4*g+2], ya[4*g+3]);
    __syncthreads();

    float y[16];
    { float acc2[16];
      const float pb = proj_b[e];
#pragma unroll
      for (int m = 0; m < 16; ++m) acc2[m] = pb;
      for (int j = 0; j < 64; ++j) {
          const float w = proj_w[j * 64 + e];
          const float4* a4 = (const float4*)&buf[j * 20];
#pragma unroll
          for (int g = 0; g < 4; ++g) {
              const float4 av = a4[g];
              acc2[4*g+0] += av.x * w; acc2[4*g+1] += av.y * w;
              acc2[4*g+2] += av.z * w; acc2[4*g+3] += av.w * w;
          }
      }
#pragma unroll
      for (int m = 0; m < 16; ++m)
          y[m] = v[(size_t)(tok0 + m) * 64 + e] + acc2[m];
    }
    __syncthreads();

    // LN over e per token, write z transposed
    { const float g2 = ln2_g[e], bb = ln2_b[e];
      float z[16];
#pragma unroll
      for (int m = 0; m < 16; ++m) {
          const float s  = waveReduceSum(y[m]);
          const float s2 = waveReduceSum(y[m] * y[m]);
          const float mu = s * (1.f / 64.f);
          const float var = s2 * (1.f / 64.f) - mu * mu;
          z[m] = (y[m] - mu) * rsqrtf(var + 1e-5f) * g2 + bb;
      }
#pragma unroll
      for (int g = 0; g < 4; ++g)
          *(float4*)&buf[e * 20 + 4*g] = make_float4(z[4*g], z[4*g+1], z[4*g+2], z[4*g+3]);
    }
    __syncthreads();

    float h[16];
    { const float b1 = m1_b[e];
#pragma unroll
      for (int m = 0; m < 16; ++m) h[m] = b1;
      for (int j = 0; j < 64; ++j) {
          const float w = m1_w[j * 64 + e];
          const float4* a4 = (const float4*)&buf[j * 20];
#pragma unroll
          for (int g = 0; g < 4; ++g) {
              const float4 av = a4[g];
              h[4*g+0] += av.x * w; h[4*g+1] += av.y * w;
              h[4*g+2] += av.z * w; h[4*g+3] += av.w * w;
          }
      }
#pragma unroll
      for (int m = 0; m < 16; ++m)
          h[m] = 0.5f * h[m] * (1.f + erff(h[m] * 0.7071067811865476f));
    }
    __syncthreads();
#pragma unroll
    for (int g = 0; g < 4; ++g)
        *(float4*)&buf[e * 20 + 4*g] = make_float4(h[4*g], h[4*g+1], h[4*g+2], h[4*g+3]);
    __syncthreads();

    { const float b2v = m2_b[e];
      float acc4[16];
#pragma unroll
      for (int m = 0; m < 16; ++m) acc4[m] = b2v;
      for (int j = 0; j < 64; ++j) {
          const float w = m2_w[j * 64 + e];
          const float4* a4 = (const float4*)&buf[j * 20];
#pragma unroll
          for (int g = 0; g < 4; ++g) {
              const float4 av = a4[g];
              acc4[4*g+0] += av.x * w; acc4[4*g+1] += av.y * w;
              acc4[4*g+2] += av.z * w; acc4[4*g+3] += av.w * w;
          }
      }
#pragma unroll
      for (int m = 0; m < 16; ++m)
          out[(size_t)(tok0 + m) * 64 + e] = y[m] + acc4[m];
    }
}

// ---------------------------------------------------------------------------
// final: unfold(3,2,1) from o2 + dense 576->768. 16 tokens/block, 256 threads,
// each thread owns 3 output columns.
// ---------------------------------------------------------------------------
__global__ __launch_bounds__(256) void final_proj(
    const float* __restrict__ o2,    // (B*T2,64)
    const float* __restrict__ w,     // (576,768)
    const float* __restrict__ bias,  // (768)
    float* __restrict__ out)         // (B*T3,768)
{
    const int tok0 = blockIdx.x * 16;
    const int tid = threadIdx.x;
    __shared__ __align__(16) float ft[D2 * 20];

    { const int c = tid & 63, grp = tid >> 6;   // grp 0..3
      for (int u = grp; u < 16 * 9; u += 4) {
          const int m = u / 9, r = u % 9;
          const int tok = tok0 + m, b = tok / T3, t = tok % T3;  // may straddle b
          const int py = t / 14, px = t % 14;
          const int ki = r / 3, kj = r % 3;
          const int iy = py * 2 - 1 + ki, ix = px * 2 - 1 + kj;
          float val = 0.f;
          if (iy >= 0 && iy < 28 && ix >= 0 && ix < 28)
              val = o2[(size_t)(b * T2 + iy * 28 + ix) * 64 + c];
          ft[(c * 9 + r) * 20 + m] = val;
      }
    }
    __syncthreads();

    float acc[3][16];
    { const float b0 = bias[tid], b1 = bias[tid + 256], b2 = bias[tid + 512];
#pragma unroll
      for (int m = 0; m < 16; ++m) { acc[0][m] = b0; acc[1][m] = b1; acc[2][m] = b2; }
    }
    for (int d = 0; d < D2; ++d) {
        const float w0 = w[d * 768 + tid];
        const float w1 = w[d * 768 + tid + 256];
        const float w2 = w[d * 768 + tid + 512];
        const float4* f4 = (const float4*)&ft[d * 20];
#pragma unroll
        for (int g = 0; g < 4; ++g) {
            const float4 f = f4[g];
            acc[0][4*g+0] += f.x * w0; acc[0][4*g+1] += f.y * w0;
            acc[0][4*g+2] += f.z * w0; acc[0][4*g+3] += f.w * w0;
            acc[1][4*g+0] += f.x * w1; acc[1][4*g+1] += f.y * w1;
            acc[1][4*g+2] += f.z * w1; acc[1][4*g+3] += f.w * w1;
            acc[2][4*g+0] += f.x * w2; acc[2][4*g+1] += f.y * w2;
            acc[2][4*g+2] += f.z * w2; acc[2][4*g+3] += f.w * w2;
        }
    }
#pragma unroll
    for (int m = 0; m < 16; ++m) {
        const size_t ob = (size_t)(tok0 + m) * 768 + tid;
        out[ob]       = acc[0][m];
        out[ob + 256] = acc[1][m];
        out[ob + 512] = acc[2][m];
    }
}

// ---------------------------------------------------------------------------
extern "C" void kernel_launch(void* const* d_in, const int* in_sizes, int n_in,
                              void* d_out, int out_size, void* d_ws, size_t ws_size,
                              hipStream_t stream) {
    const float* x         = (const float*)d_in[0];
    const float* p1_kqv_w  = (const float*)d_in[1];
    const float* p1_kqv_b  = (const float*)d_in[2];
    const float* p1_proj_w = (const float*)d_in[3];
    const float* p1_proj_b = (const float*)d_in[4];
    const float* p1_ln1_g  = (const float*)d_in[5];
    const float* p1_ln1_b  = (const float*)d_in[6];
    const float* p1_ln2_g  = (const float*)d_in[7];
    const float* p1_ln2_b  = (const float*)d_in[8];
    const float* p1_m1_w   = (const float*)d_in[9];
    const float* p1_m1_b   = (const float*)d_in[10];
    const float* p1_m2_w   = (const float*)d_in[11];
    const float* p1_m2_b   = (const float*)d_in[12];
    const float* p1_rf     = (const float*)d_in[13];
    const float* p2_kqv_w  = (const float*)d_in[14];
    const float* p2_kqv_b  = (const float*)d_in[15];
    const float* p2_proj_w = (const float*)d_in[16];
    const float* p2_proj_b = (const float*)d_in[17];
    const float* p2_ln1_g  = (const float*)d_in[18];
    const float* p2_ln1_b  = (const float*)d_in[19];
    const float* p2_ln2_g  = (const float*)d_in[20];
    const float* p2_ln2_b  = (const float*)d_in[21];
    const float* p2_m1_w   = (const float*)d_in[22];
    const float* p2_m1_b   = (const float*)d_in[23];
    const float* p2_m2_w   = (const float*)d_in[24];
    const float* p2_m2_b   = (const float*)d_in[25];
    const float* p2_rf     = (const float*)d_in[26];
    const float* proj_w    = (const float*)d_in[27];
    const float* proj_b    = (const float*)d_in[28];

    float* ws = (float*)d_ws;
    size_t off = 0;
    // Zeroed region first (one memset covers all four reduction buffers)
    float* ksum1 = ws + off; off += (size_t)NB * 32;
    float* kptv1 = ws + off; off += (size_t)NB * 64 * 32;
    float* ksum2 = ws + off; off += (size_t)NB * 32;
    float* kptv2 = ws + off; off += (size_t)NB * 64 * 32;
    const size_t zero_bytes = off * sizeof(float);
    // Stage-1 buffers
    float* kp1 = ws + off; off += (size_t)NB * T1 * 32;   // dead after reduce_kv1
    float* qp1 = ws + off; off += (size_t)NB * T1 * 32;   // dead after epilogue1
    float* v1  = ws + off; off += (size_t)NB * T1 * 64;   // dead after epilogue1
    float* o1  = ws + off; off += (size_t)NB * T1 * 64;   // dead after front2
    // Stage-2 aliases onto dead kp1/qp1 region (9.6M floats < 12.8M)
    size_t off2 = 0;
    float* kp2 = kp1 + off2; off2 += (size_t)NB * T2 * 32;
    float* qp2 = kp1 + off2; off2 += (size_t)NB * T2 * 32;
    float* v2  = kp1 + off2; off2 += (size_t)NB * T2 * 64;
    float* o2  = kp1 + off2; off2 += (size_t)NB * T2 * 64;

    hipMemsetAsync(ws, 0, zero_bytes, stream);

    front1<<<NB * T1 / 32, 192, 0, stream>>>(x, p1_kqv_w, p1_kqv_b, p1_ln1_g,
                                             p1_ln1_b, p1_rf, kp1, qp1, v1);
    reduce_kv<T1, 14><<<NB * 14, 256, 0, stream>>>(kp1, v1, ksum1, kptv1);
    epilogue<T1><<<NB * T1 / 16, 64, 0, stream>>>(qp1, v1, ksum1, kptv1,
                                                  p1_proj_w, p1_proj_b, p1_ln2_g, p1_ln2_b,
                                                  p1_m1_w, p1_m1_b, p1_m2_w, p1_m2_b, o1);
    front2<<<NB * T2 / 16, 192, 0, stream>>>(o1, p2_kqv_w, p2_kqv_b, p2_ln1_g,
                                             p2_ln1_b, p2_rf, kp2, qp2, v2);
    reduce_kv<T2, 7><<<NB * 7, 256, 0, stream>>>(kp2, v2, ksum2, kptv2);
    epilogue<T2><<<NB * T2 / 16, 64, 0, stream>>>(qp2, v2, ksum2, kptv2,
                                                  p2_proj_w, p2_proj_b, p2_ln2_g, p2_ln2_b,
                                                  p2_m1_w, p2_m1_b, p2_m2_w, p2_m2_b, o2);
    final_proj<<<NB * T3 / 16, 256, 0, stream>>>(o2, proj_w, proj_b, (float*)d_out);
}